// Round 11
// baseline (711.459 us; speedup 1.0000x reference)
//
#include <hip/hip_runtime.h>
#include <hip/hip_bf16.h>

#define C_ 256
#define N_ 4096
#define CN (C_*N_)
#define EPSF 1e-5f
#define NS_ITERS 6
#define KSPLIT 8

#if defined(__has_builtin)
#if __has_builtin(__builtin_amdgcn_global_load_lds)
#define HAS_GLL 1
#endif
#endif

__device__ __forceinline__ int refl(int t) {
  return t < 0 ? -t : (t > 63 ? 126 - t : t);
}

__device__ __forceinline__ void fma16(float acc[4][4], float a0, float a1, float a2, float a3, float4 b) {
  acc[0][0] += a0*b.x; acc[0][1] += a0*b.y; acc[0][2] += a0*b.z; acc[0][3] += a0*b.w;
  acc[1][0] += a1*b.x; acc[1][1] += a1*b.y; acc[1][2] += a1*b.z; acc[1][3] += a1*b.w;
  acc[2][0] += a2*b.x; acc[2][1] += a2*b.y; acc[2][2] += a2*b.z; acc[2][3] += a2*b.w;
  acc[3][0] += a3*b.x; acc[3][1] += a3*b.y; acc[3][2] += a3*b.z; acc[3][3] += a3*b.w;
}

// ---------------- means: m in {0,1}=content b, {2,3}=style b ----------------
__global__ __launch_bounds__(256) void k_mean(const float* content, const float* style,
                                              float* means) {
  int c = blockIdx.x, m = blockIdx.y, t = threadIdx.x;
  const float* x = (m < 2 ? content : style) + (size_t)(m & 1) * CN + (size_t)c * N_;
  float s = 0.f;
  for (int i = t; i < N_; i += 256) s += x[i];
  __shared__ float red[256];
  red[t] = s; __syncthreads();
  for (int off = 128; off > 0; off >>= 1) { if (t < off) red[t] += red[t + off]; __syncthreads(); }
  if (t == 0) means[m * C_ + c] = red[0] * (1.f / N_);
}

// ---------------- covariance raw sums, split-K (32x32 tiles, 8 k-chunks) ----------------
__global__ __launch_bounds__(256) void k_cov(const float* content, const float* style,
                                             float* covp) {
  int m = blockIdx.y, kc = blockIdx.z;
  int ti = blockIdx.x >> 3, tj = blockIdx.x & 7;
  int t = threadIdx.x, tx = t & 15, ty = t >> 4;
  const float* x = (m < 2 ? content : style) + (size_t)(m & 1) * CN;
  __shared__ float As[32][33], Bs[32][33];
  float acc[2][2] = {};
  int i0 = ti * 32, j0 = tj * 32;
  int kbeg = kc * (N_ / KSPLIT), kend = kbeg + (N_ / KSPLIT);
  for (int k0 = kbeg; k0 < kend; k0 += 32) {
#pragma unroll
    for (int l = 0; l < 4; l++) {
      int e = t + l * 256;
      int rr = e >> 5, nn = e & 31;
      As[rr][nn] = x[(size_t)(i0 + rr) * N_ + k0 + nn];
      Bs[rr][nn] = x[(size_t)(j0 + rr) * N_ + k0 + nn];
    }
    __syncthreads();
#pragma unroll
    for (int kk = 0; kk < 32; kk++) {
      float a0 = As[ty*2][kk], a1 = As[ty*2+1][kk];
      float b0 = Bs[tx*2][kk], b1 = Bs[tx*2+1][kk];
      acc[0][0] += a0*b0; acc[0][1] += a0*b1; acc[1][0] += a1*b0; acc[1][1] += a1*b1;
    }
    __syncthreads();
  }
#pragma unroll
  for (int a = 0; a < 2; a++)
#pragma unroll
    for (int b = 0; b < 2; b++)
      covp[((size_t)kc*4 + m)*65536 + (size_t)(i0 + ty*2 + a)*C_ + (j0 + tx*2 + b)] = acc[a][b];
}

// ---------------- trace directly from covp partials -> cnrm = (tr/256)*1.3 ----------------
__global__ __launch_bounds__(256) void k_trace2(const float* covp, const float* means,
                                                float* cnrm) {
  int m = blockIdx.x, t = threadIdx.x;
  float s = 0.f;
#pragma unroll
  for (int kc = 0; kc < KSPLIT; kc++)
    s += covp[((size_t)kc*4 + m)*65536 + (size_t)t*257];
  float mi = means[m*C_ + t];
  float d = (s - (float)N_*mi*mi) * (1.f/(float)(N_-1));
  __shared__ float red[256];
  red[t] = d; __syncthreads();
  for (int off = 128; off > 0; off >>= 1) { if (t < off) red[t] += red[t + off]; __syncthreads(); }
  if (!t) cnrm[m] = red[0] * (1.3f/256.f);
}

// ---------------- merged: covred + nsinit (cov buffer eliminated) ----------------
__global__ __launch_bounds__(256) void k_covred_init(const float* covp, const float* means,
                                                     const float* cnrm, float* Y, float* Z) {
  int i = blockIdx.x, m = blockIdx.y, j = threadIdx.x;
  float s = 0.f;
#pragma unroll
  for (int kc = 0; kc < KSPLIT; kc++)
    s += covp[((size_t)kc*4 + m)*65536 + (size_t)i*C_ + j];
  float mi = means[m*C_ + i], mj = means[m*C_ + j];
  float cv = (s - (float)N_*mi*mj) * (1.f/(float)(N_-1));
  size_t o = (size_t)m*65536 + (size_t)i*C_ + j;
  Y[o] = cv / cnrm[m];
  Z[o] = (i == j) ? 1.f : 0.f;
}

// ---------------- NS phase A: T = 3I - Z*Y (32x32 tiles, 256 blocks) ----------------
__global__ __launch_bounds__(256) void k_nsA(const float* Zin, const float* Yin, float* T) {
  int m = blockIdx.y;
  const float* A = Zin + (size_t)m*65536;
  const float* B = Yin + (size_t)m*65536;
  float* O = T + (size_t)m*65536;
  __shared__ float As[32][33], Bs[32][33];
  int t = threadIdx.x, tx = t & 15, ty = t >> 4;
  int m0 = (blockIdx.x >> 3) * 32, n0 = (blockIdx.x & 7) * 32;
  float acc[2][2] = {};
  for (int k0 = 0; k0 < 256; k0 += 32) {
#pragma unroll
    for (int l = 0; l < 4; l++) {
      int e = t + l * 256;
      int rr = e >> 5, cc = e & 31;
      As[rr][cc] = A[(size_t)(m0+rr)*256 + k0+cc];
      Bs[rr][cc] = B[(size_t)(k0+rr)*256 + n0+cc];
    }
    __syncthreads();
#pragma unroll
    for (int kk = 0; kk < 32; kk++) {
      float a0 = As[ty*2][kk], a1 = As[ty*2+1][kk];
      float b0 = Bs[kk][tx*2], b1 = Bs[kk][tx*2+1];
      acc[0][0] += a0*b0; acc[0][1] += a0*b1; acc[1][0] += a1*b0; acc[1][1] += a1*b1;
    }
    __syncthreads();
  }
#pragma unroll
  for (int a = 0; a < 2; a++)
#pragma unroll
    for (int b = 0; b < 2; b++) {
      int r = m0 + ty*2 + a, c = n0 + tx*2 + b;
      O[(size_t)r*256 + c] = (r == c) ? 3.f - acc[a][b] : -acc[a][b];
    }
}

// ---------------- NS phase B: Y'=0.5*Y*T (z=0), Z'=0.5*T*Z (z=1) ----------------
__global__ __launch_bounds__(256) void k_nsB(const float* Yin, const float* Zin, const float* T,
                                             float* Yout, float* Zout) {
  int m = blockIdx.y, z = blockIdx.z;
  const float* A = (z == 0 ? Yin : T) + (size_t)m*65536;
  const float* B = (z == 0 ? T : Zin) + (size_t)m*65536;
  float* O = (z == 0 ? Yout : Zout) + (size_t)m*65536;
  __shared__ float As[32][33], Bs[32][33];
  int t = threadIdx.x, tx = t & 15, ty = t >> 4;
  int m0 = (blockIdx.x >> 3) * 32, n0 = (blockIdx.x & 7) * 32;
  float acc[2][2] = {};
  for (int k0 = 0; k0 < 256; k0 += 32) {
#pragma unroll
    for (int l = 0; l < 4; l++) {
      int e = t + l * 256;
      int rr = e >> 5, cc = e & 31;
      As[rr][cc] = A[(size_t)(m0+rr)*256 + k0+cc];
      Bs[rr][cc] = B[(size_t)(k0+rr)*256 + n0+cc];
    }
    __syncthreads();
#pragma unroll
    for (int kk = 0; kk < 32; kk++) {
      float a0 = As[ty*2][kk], a1 = As[ty*2+1][kk];
      float b0 = Bs[kk][tx*2], b1 = Bs[kk][tx*2+1];
      acc[0][0] += a0*b0; acc[0][1] += a0*b1; acc[1][0] += a1*b0; acc[1][1] += a1*b1;
    }
    __syncthreads();
  }
#pragma unroll
  for (int a = 0; a < 2; a++)
#pragma unroll
    for (int b = 0; b < 2; b++)
      O[(size_t)(m0+ty*2+a)*256 + n0+tx*2+b] = 0.5f * acc[a][b];
}

// ---------------- whiten (all 4 matrices in grid.z): out = (1/sqrt(c))*Z@(x-mean) ----------------
__global__ __launch_bounds__(256) void k_whiten(const float* content, const float* style,
                                                const float* Zall, const float* means,
                                                const float* cnrm, float* nc, float* ns) {
  int m = blockIdx.z;
  const float* x = (m < 2 ? content : style) + (size_t)(m & 1) * CN;
  float* outp = (m < 2 ? nc : ns) + (size_t)(m & 1) * CN;
  const float* Zm = Zall + (size_t)m*65536;
  const float* mean = means + m*C_;
  __shared__ float As[16][68], Bs[16][64];
  int t = threadIdx.x, tx = t & 15, ty = t >> 4;
  int n0 = blockIdx.x * 64, m0 = blockIdx.y * 64;
  float acc[4][4] = {};
  for (int k0 = 0; k0 < 256; k0 += 16) {
#pragma unroll
    for (int l = 0; l < 4; l++) {
      int e = t + l*256;
      { int kk = e & 15, mm = e >> 4; As[kk][mm] = Zm[(size_t)(m0+mm)*256 + k0+kk]; }
      { int nn = e & 63, kk = e >> 6;
        Bs[kk][nn] = x[(size_t)(k0+kk)*N_ + n0+nn] - mean[k0+kk]; }
    }
    __syncthreads();
#pragma unroll
    for (int kk = 0; kk < 16; kk++) {
      float4 b = *(const float4*)&Bs[kk][tx*4];
      fma16(acc, As[kk][ty*4+0], As[kk][ty*4+1], As[kk][ty*4+2], As[kk][ty*4+3], b);
    }
    __syncthreads();
  }
  float scale = 1.0f / sqrtf(cnrm[m]);
#pragma unroll
  for (int i = 0; i < 4; i++) {
    float4 o = make_float4(acc[i][0]*scale, acc[i][1]*scale, acc[i][2]*scale, acc[i][3]*scale);
    *(float4*)&outp[(size_t)(m0+ty*4+i)*N_ + n0 + tx*4] = o;
  }
}

// ---------------- per-pixel channel sum-of-squares of ns ----------------
__global__ __launch_bounds__(256) void k_ssq(const float* ns, float* ssq) {
  int b = blockIdx.y; int p = blockIdx.x * 256 + threadIdx.x;
  float acc = 0.f;
  for (int c = 0; c < C_; c++) { float v = ns[(size_t)b*CN + (size_t)c*N_ + p]; acc += v*v; }
  ssq[b*N_ + p] = acc;
}

// ---------------- patch reciprocal norms ----------------
__global__ __launch_bounds__(256) void k_rnorm(const float* ssq, float* rnorm) {
  int b = blockIdx.y; int s = blockIdx.x * 256 + threadIdx.x;
  int sy = s >> 6, sx = s & 63;
  float sum = 0.f;
#pragma unroll
  for (int ky = 0; ky < 3; ky++)
#pragma unroll
    for (int kx = 0; kx < 3; kx++)
      sum += ssq[b*N_ + refl(sy+ky-1)*64 + refl(sx+kx-1)];
  rnorm[b*N_ + s] = 1.f / (sqrtf(sum) + EPSF);
}

// ---------------- transpose ns -> ns_t [b][pixel][channel] ----------------
__global__ __launch_bounds__(256) void k_transpose(const float* ns, float* ns_t) {
  int b = blockIdx.z;
  int u0 = blockIdx.x * 32, c0 = blockIdx.y * 32;
  __shared__ float tile[32][33];
  int t = threadIdx.x;
#pragma unroll
  for (int l = 0; l < 4; l++) {
    int e = t + l*256; int cc = e >> 5, uu = e & 31;
    tile[cc][uu] = ns[(size_t)b*CN + (size_t)(c0+cc)*N_ + u0+uu];
  }
  __syncthreads();
#pragma unroll
  for (int l = 0; l < 4; l++) {
    int e = t + l*256; int uu = e >> 5, cc = e & 31;
    ns_t[(size_t)b*CN + (size_t)(u0+uu)*C_ + c0+cc] = tile[cc][uu];
  }
}

// ---------------- Gram (128x128, 512 thr, acc 8x4, BK=32, DOUBLE-BUFFERED DMA staging) ----------------
// r10 + LDS double-buffer: DMA for tile k+1 issued BEFORE computing tile k, so the
// vmcnt(0) drain at the barrier is ~free (DMA had 2048 VALU cycles to complete).
// DMA staging uses ZERO VGPRs -> no register-pressure trap (r5/r9 register prefetch died at
// the 128-VGPR cliff; r10 proved DMA staging holds VGPR=44).
__global__ __launch_bounds__(512) void k_gram(const float* nc, const float* ns, float* Hx) {
  // 2 bufs x (As[32][128] + Bs[32][128]) = 16384 floats = 64 KB; epilogue Gs[64][133] unioned
  __shared__ float smem[16384];
  int t = threadIdx.x;
  int v0 = blockIdx.y * 128, u0 = blockIdx.x * 128;
  int wave = t >> 6, lane = t & 63;
  int wv = wave >> 1, wu = wave & 1;        // wave tile: rows wv*32..+31, cols wu*64..+63
  int ly = lane >> 4, lx = lane & 15;
  int srow = t >> 5, scol = (t & 31) * 4;   // 512 thr = 16 rows x 32 col-groups per DMA pass
  float acc[8][4] = {};
#ifdef HAS_GLL
#define GLL(srcp, dstp) __builtin_amdgcn_global_load_lds( \
    (const __attribute__((address_space(1))) void*)(srcp), \
    (__attribute__((address_space(3))) void*)(dstp), 16, 0, 0)
  GLL(&nc[(size_t)srow*N_ + v0 + scol],      &smem[srow*128 + scol]);
  GLL(&nc[(size_t)(16+srow)*N_ + v0 + scol], &smem[(srow+16)*128 + scol]);
  GLL(&ns[(size_t)srow*N_ + u0 + scol],      &smem[4096 + srow*128 + scol]);
  GLL(&ns[(size_t)(16+srow)*N_ + u0 + scol], &smem[4096 + (srow+16)*128 + scol]);
#else
  *(float4*)&smem[srow*128 + scol]        = *(const float4*)&nc[(size_t)srow*N_ + v0 + scol];
  *(float4*)&smem[(srow+16)*128 + scol]   = *(const float4*)&nc[(size_t)(16+srow)*N_ + v0 + scol];
  *(float4*)&smem[4096 + srow*128 + scol]      = *(const float4*)&ns[(size_t)srow*N_ + u0 + scol];
  *(float4*)&smem[4096 + (srow+16)*128 + scol] = *(const float4*)&ns[(size_t)(16+srow)*N_ + u0 + scol];
#endif
  __syncthreads();
  for (int k0 = 0; k0 < 256; k0 += 32) {
    int cur = (k0 >> 5) & 1;
    const float* As = smem + cur*8192;
    const float* Bs = As + 4096;
    if (k0 + 32 < 256) {                      // prefetch next tile into the other buffer
      float* An = smem + (cur^1)*8192;
      float* Bn = An + 4096;
#ifdef HAS_GLL
      GLL(&nc[(size_t)(k0+32+srow)*N_ + v0 + scol], &An[srow*128 + scol]);
      GLL(&nc[(size_t)(k0+48+srow)*N_ + v0 + scol], &An[(srow+16)*128 + scol]);
      GLL(&ns[(size_t)(k0+32+srow)*N_ + u0 + scol], &Bn[srow*128 + scol]);
      GLL(&ns[(size_t)(k0+48+srow)*N_ + u0 + scol], &Bn[(srow+16)*128 + scol]);
#else
      *(float4*)&An[srow*128 + scol]      = *(const float4*)&nc[(size_t)(k0+32+srow)*N_ + v0 + scol];
      *(float4*)&An[(srow+16)*128 + scol] = *(const float4*)&nc[(size_t)(k0+48+srow)*N_ + v0 + scol];
      *(float4*)&Bn[srow*128 + scol]      = *(const float4*)&ns[(size_t)(k0+32+srow)*N_ + u0 + scol];
      *(float4*)&Bn[(srow+16)*128 + scol] = *(const float4*)&ns[(size_t)(k0+48+srow)*N_ + u0 + scol];
#endif
    }
#pragma unroll
    for (int kk = 0; kk < 32; kk++) {
      float4 a0 = *(const float4*)&As[kk*128 + wv*32 + ly*8];      // lane-broadcast across lx
      float4 a1 = *(const float4*)&As[kk*128 + wv*32 + ly*8 + 4];
      float4 b0 = *(const float4*)&Bs[kk*128 + wu*64 + lx*4];
      float ar[8] = {a0.x,a0.y,a0.z,a0.w,a1.x,a1.y,a1.z,a1.w};
#pragma unroll
      for (int i = 0; i < 8; i++) {
        acc[i][0] += ar[i]*b0.x; acc[i][1] += ar[i]*b0.y;
        acc[i][2] += ar[i]*b0.z; acc[i][3] += ar[i]*b0.w;
      }
    }
    __syncthreads();
  }
  // epilogue: per 64-row half h, x-diagonal blur. Gs stride 133 keeps writes <=2-way.
  float* Gs = smem;  // [64][133]
  int btx = t & 15, bty = t >> 4;            // bty 0..31
#pragma unroll
  for (int h = 0; h < 2; h++) {
    __syncthreads();
    if ((wv >> 1) == h) {                    // waves 2h, 2h+1 own rows h*64..h*64+63
      int rbase = (wv & 1) * 32;
#pragma unroll
      for (int i = 0; i < 8; i++) {
        int row = rbase + ly*8 + i;
#pragma unroll
        for (int j = 0; j < 4; j++)
          Gs[row*133 + wu*64 + lx*4 + j] = acc[i][j];
      }
    }
    __syncthreads();
#pragma unroll
    for (int i = 0; i < 2; i++) {
      int px = bty*2 + i;
      int xm = refl(px-1), xp = refl(px+1);
#pragma unroll
      for (int jh = 0; jh < 2; jh++) {       // col halves (sy blocks)
        int ub = jh*64;
        float tmp[4];
#pragma unroll
        for (int j = 0; j < 4; j++) {
          int sx = btx*4 + j;
          int sm = refl(sx-1), sp = refl(sx+1);
          tmp[j] = Gs[xm*133 + ub + sm] + Gs[px*133 + ub + sx] + Gs[xp*133 + ub + sp];
        }
        *(float4*)&Hx[(size_t)(v0 + h*64 + px)*N_ + u0 + ub + btx*4] =
            make_float4(tmp[0], tmp[1], tmp[2], tmp[3]);
      }
    }
  }
}

// ---------------- y-diagonal blur of Hx + argmax; 4 consecutive py per block ----------------
// Adjacent py share 2 of 3 Hx rows -> L1/L2 reuse cuts Hx read traffic ~2x.
__global__ __launch_bounds__(256) void k_argmax(const float* Hx, const float* rnorm,
                                                int* idx, int b) {
  int g = blockIdx.x;                  // 1024 groups
  int pg = g >> 6, px = g & 63;
  int t = threadIdx.x;
  __shared__ float sv[256]; __shared__ int si[256];
#pragma unroll
  for (int i = 0; i < 4; i++) {
    int py = pg*4 + i;
    int p = py*64 + px;
    size_t r0 = (size_t)(refl(py-1)*64 + px) * N_;
    size_t r1 = (size_t)p * N_;
    size_t r2 = (size_t)(refl(py+1)*64 + px) * N_;
    float bv = -1e30f; int bs = 0;
    for (int s = t; s < N_; s += 256) {
      int sy = s >> 6, sx = s & 63;
      int u0 = refl(sy-1)*64 + sx, u2 = refl(sy+1)*64 + sx;
      float acc = Hx[r0 + u0] + Hx[r1 + s] + Hx[r2 + u2];
      float sc = acc * rnorm[b*N_ + s];
      if (sc > bv) { bv = sc; bs = s; }   // ascending s -> first occurrence kept
    }
    sv[t] = bv; si[t] = bs; __syncthreads();
    for (int off = 128; off > 0; off >>= 1) {
      if (t < off) {
        if (sv[t+off] > sv[t] || (sv[t+off] == sv[t] && si[t+off] < si[t])) {
          sv[t] = sv[t+off]; si[t] = si[t+off];
        }
      }
      __syncthreads();
    }
    if (!t) idx[b*N_ + p] = si[0];
    __syncthreads();
  }
}

// ---------------- deconv gather: recont[b][p][c] ----------------
__global__ __launch_bounds__(256) void k_recon(const float* ns_t, const int* idx, float* recont) {
  int p = blockIdx.x, b = blockIdx.y, c = threadIdx.x;
  int py = p >> 6, px = p & 63;
  float acc = 0.f;
#pragma unroll
  for (int dy = 0; dy < 3; dy++)
#pragma unroll
    for (int dx = 0; dx < 3; dx++) {
      int q = refl(py+dy-1)*64 + refl(px+dx-1);
      int s = idx[b*N_ + q];
      int sy = s >> 6, sx = s & 63;
      int src = refl(sy+1-dy)*64 + refl(sx+1-dx);
      acc += ns_t[(size_t)b*CN + (size_t)src*C_ + c];
    }
  float dc = ((py==0||py==63)?2.f:3.f) * ((px==0||px==63)?2.f:3.f);
  recont[(size_t)b*CN + (size_t)p*C_ + c] = acc / dc;
}

// ---------------- coloring (both batches via grid.z): out = sqrt(c)*(Ys@recon)+smean ----------------
__global__ __launch_bounds__(256) void k_color(const float* Yall, const float* recont_all,
                                               const float* cnrm, const float* means,
                                               float* out_all) {
  int b = blockIdx.z;
  const float* Ym = Yall + (size_t)(2+b)*65536;
  const float* recont = recont_all + (size_t)b*CN;
  const float* smean = means + (2+b)*C_;
  float* out = out_all + (size_t)b*CN;
  __shared__ float As[16][68], Bs[16][68];
  int t = threadIdx.x, tx = t & 15, ty = t >> 4;
  int n0 = blockIdx.x * 64, m0 = blockIdx.y * 64;
  float acc[4][4] = {};
  for (int k0 = 0; k0 < 256; k0 += 16) {
#pragma unroll
    for (int l = 0; l < 4; l++) {
      int e = t + l*256;
      int kk = e & 15, q = e >> 4;
      As[kk][q] = Ym[(size_t)(m0+q)*256 + k0+kk];
      Bs[kk][q] = recont[(size_t)(n0+q)*256 + k0+kk];
    }
    __syncthreads();
#pragma unroll
    for (int kk = 0; kk < 16; kk++) {
      float4 b4 = make_float4(Bs[kk][tx*4+0], Bs[kk][tx*4+1], Bs[kk][tx*4+2], Bs[kk][tx*4+3]);
      fma16(acc, As[kk][ty*4+0], As[kk][ty*4+1], As[kk][ty*4+2], As[kk][ty*4+3], b4);
    }
    __syncthreads();
  }
  float scale = sqrtf(cnrm[2+b]);
#pragma unroll
  for (int i = 0; i < 4; i++) {
    int r = m0 + ty*4 + i;
    float sm = smean[r];
    float4 o = make_float4(acc[i][0]*scale + sm, acc[i][1]*scale + sm,
                           acc[i][2]*scale + sm, acc[i][3]*scale + sm);
    *(float4*)&out[(size_t)r*N_ + n0 + tx*4] = o;
  }
}

extern "C" void kernel_launch(void* const* d_in, const int* in_sizes, int n_in,
                              void* d_out, int out_size, void* d_ws, size_t ws_size,
                              hipStream_t stream) {
  const float* content = (const float*)d_in[0];
  const float* style   = (const float*)d_in[1];
  float* out = (float*)d_out;

  // workspace layout (floats); total ~107 MiB
  float* F = (float*)d_ws;
  float* means  = F + 0;         // 4*256
  float* cnrm   = F + 1024;      // 4
  float* Y      = F + 264192;
  float* Z      = F + 526336;
  float* Y2     = F + 788480;
  float* Z2     = F + 1050624;
  float* T      = F + 1312768;
  float* nc     = F + 1574912;   // 2*CN
  float* ns     = F + 3672064;   // 2*CN
  float* ns_t   = F + 5769216;   // 2*CN
  float* recont = F + 7866368;   // 2*CN
  float* ssq    = F + 9963520;   // 2*4096
  float* rnorm  = F + 9971712;   // 2*4096
  int*   idx    = (int*)(F + 9979904); // 2*4096
  float* Hx     = F + 9988096;   // 4096*4096 (reused per batch)

  // split-K cov partials (8 MB) alias the nc buffer: consumed by k_trace2/k_covred_init
  // before k_whiten writes nc (stream-serialized).
  float* covp = nc;

  // 1. per-channel means
  k_mean<<<dim3(256,4), 256, 0, stream>>>(content, style, means);
  // 2. covariance raw sums, split-K (2048 blocks)
  k_cov<<<dim3(64,4,KSPLIT), 256, 0, stream>>>(content, style, covp);
  // 3. trace from partials -> cnrm = (tr/256)*1.3 (spectrum-centered NS scaling)
  k_trace2<<<4, 256, 0, stream>>>(covp, means, cnrm);
  // 4. merged covred + NS init (cov matrix never materialized)
  k_covred_init<<<dim3(256,4), 256, 0, stream>>>(covp, means, cnrm, Y, Z);
  // 5. NS iterations, discrete launches (r7: grid barriers cost ~40us each — launches win).
  float *Ya = Y, *Za = Z, *Yb = Y2, *Zb = Z2;
  for (int it = 0; it < NS_ITERS; it++) {
    k_nsA<<<dim3(64,4), 256, 0, stream>>>(Za, Ya, T);
    k_nsB<<<dim3(64,4,2), 256, 0, stream>>>(Ya, Za, T, Yb, Zb);
    float* tmp;
    tmp = Ya; Ya = Yb; Yb = tmp;
    tmp = Za; Za = Zb; Zb = tmp;
  }
  // 6. whitening: nc, ns (all 4 matrices, one launch); NS_ITERS even -> results in Y,Z
  k_whiten<<<dim3(64,4,4), 256, 0, stream>>>(content, style, Za, means, cnrm, nc, ns);
  // 7. patch norms of whitened style
  k_ssq<<<dim3(16,2), 256, 0, stream>>>(ns, ssq);
  k_rnorm<<<dim3(16,2), 256, 0, stream>>>(ssq, rnorm);
  // 8. pixel-major transpose of ns for the recon gather
  k_transpose<<<dim3(128,8,2), 256, 0, stream>>>(ns, ns_t);
  // 9. per batch: Gram+x-blur (double-buffered DMA), then y-blur+argmax (4 py/block)
  for (int b = 0; b < 2; b++) {
    k_gram<<<dim3(32,32), 512, 0, stream>>>(nc + (size_t)b*CN, ns + (size_t)b*CN, Hx);
    k_argmax<<<1024, 256, 0, stream>>>(Hx, rnorm, idx, b);
  }
  // 10. deconv gather + deconv-norm division
  k_recon<<<dim3(4096,2), 256, 0, stream>>>(ns_t, idx, recont);
  // 11. coloring with style stats (both batches, one launch)
  k_color<<<dim3(64,4,2), 256, 0, stream>>>(Ya, recont, cnrm, means, out);
}

// Round 12
// 602.875 us; speedup vs baseline: 1.1801x; 1.1801x over previous
//
#include <hip/hip_runtime.h>
#include <hip/hip_bf16.h>

#define C_ 256
#define N_ 4096
#define CN (C_*N_)
#define EPSF 1e-5f
#define NS_ITERS 6
#define KSPLIT 8

#if defined(__has_builtin)
#if __has_builtin(__builtin_amdgcn_global_load_lds)
#define HAS_GLL 1
#endif
#endif

__device__ __forceinline__ int refl(int t) {
  return t < 0 ? -t : (t > 63 ? 126 - t : t);
}

__device__ __forceinline__ void fma16(float acc[4][4], float a0, float a1, float a2, float a3, float4 b) {
  acc[0][0] += a0*b.x; acc[0][1] += a0*b.y; acc[0][2] += a0*b.z; acc[0][3] += a0*b.w;
  acc[1][0] += a1*b.x; acc[1][1] += a1*b.y; acc[1][2] += a1*b.z; acc[1][3] += a1*b.w;
  acc[2][0] += a2*b.x; acc[2][1] += a2*b.y; acc[2][2] += a2*b.z; acc[2][3] += a2*b.w;
  acc[3][0] += a3*b.x; acc[3][1] += a3*b.y; acc[3][2] += a3*b.z; acc[3][3] += a3*b.w;
}

// ---------------- means: m in {0,1}=content b, {2,3}=style b ----------------
__global__ __launch_bounds__(256) void k_mean(const float* content, const float* style,
                                              float* means) {
  int c = blockIdx.x, m = blockIdx.y, t = threadIdx.x;
  const float* x = (m < 2 ? content : style) + (size_t)(m & 1) * CN + (size_t)c * N_;
  float s = 0.f;
  for (int i = t; i < N_; i += 256) s += x[i];
  __shared__ float red[256];
  red[t] = s; __syncthreads();
  for (int off = 128; off > 0; off >>= 1) { if (t < off) red[t] += red[t + off]; __syncthreads(); }
  if (t == 0) means[m * C_ + c] = red[0] * (1.f / N_);
}

// ---------------- covariance raw sums, split-K (32x32 tiles, 8 k-chunks) ----------------
__global__ __launch_bounds__(256) void k_cov(const float* content, const float* style,
                                             float* covp) {
  int m = blockIdx.y, kc = blockIdx.z;
  int ti = blockIdx.x >> 3, tj = blockIdx.x & 7;
  int t = threadIdx.x, tx = t & 15, ty = t >> 4;
  const float* x = (m < 2 ? content : style) + (size_t)(m & 1) * CN;
  __shared__ float As[32][33], Bs[32][33];
  float acc[2][2] = {};
  int i0 = ti * 32, j0 = tj * 32;
  int kbeg = kc * (N_ / KSPLIT), kend = kbeg + (N_ / KSPLIT);
  for (int k0 = kbeg; k0 < kend; k0 += 32) {
#pragma unroll
    for (int l = 0; l < 4; l++) {
      int e = t + l * 256;
      int rr = e >> 5, nn = e & 31;
      As[rr][nn] = x[(size_t)(i0 + rr) * N_ + k0 + nn];
      Bs[rr][nn] = x[(size_t)(j0 + rr) * N_ + k0 + nn];
    }
    __syncthreads();
#pragma unroll
    for (int kk = 0; kk < 32; kk++) {
      float a0 = As[ty*2][kk], a1 = As[ty*2+1][kk];
      float b0 = Bs[tx*2][kk], b1 = Bs[tx*2+1][kk];
      acc[0][0] += a0*b0; acc[0][1] += a0*b1; acc[1][0] += a1*b0; acc[1][1] += a1*b1;
    }
    __syncthreads();
  }
#pragma unroll
  for (int a = 0; a < 2; a++)
#pragma unroll
    for (int b = 0; b < 2; b++)
      covp[((size_t)kc*4 + m)*65536 + (size_t)(i0 + ty*2 + a)*C_ + (j0 + tx*2 + b)] = acc[a][b];
}

// ---------------- trace directly from covp partials -> cnrm = (tr/256)*1.3 ----------------
__global__ __launch_bounds__(256) void k_trace2(const float* covp, const float* means,
                                                float* cnrm) {
  int m = blockIdx.x, t = threadIdx.x;
  float s = 0.f;
#pragma unroll
  for (int kc = 0; kc < KSPLIT; kc++)
    s += covp[((size_t)kc*4 + m)*65536 + (size_t)t*257];
  float mi = means[m*C_ + t];
  float d = (s - (float)N_*mi*mi) * (1.f/(float)(N_-1));
  __shared__ float red[256];
  red[t] = d; __syncthreads();
  for (int off = 128; off > 0; off >>= 1) { if (t < off) red[t] += red[t + off]; __syncthreads(); }
  if (!t) cnrm[m] = red[0] * (1.3f/256.f);
}

// ---------------- merged: covred + nsinit (cov buffer eliminated) ----------------
__global__ __launch_bounds__(256) void k_covred_init(const float* covp, const float* means,
                                                     const float* cnrm, float* Y, float* Z) {
  int i = blockIdx.x, m = blockIdx.y, j = threadIdx.x;
  float s = 0.f;
#pragma unroll
  for (int kc = 0; kc < KSPLIT; kc++)
    s += covp[((size_t)kc*4 + m)*65536 + (size_t)i*C_ + j];
  float mi = means[m*C_ + i], mj = means[m*C_ + j];
  float cv = (s - (float)N_*mi*mj) * (1.f/(float)(N_-1));
  size_t o = (size_t)m*65536 + (size_t)i*C_ + j;
  Y[o] = cv / cnrm[m];
  Z[o] = (i == j) ? 1.f : 0.f;
}

// ---------------- NS phase A: T = 3I - Z*Y (32x32 tiles, 256 blocks) ----------------
__global__ __launch_bounds__(256) void k_nsA(const float* Zin, const float* Yin, float* T) {
  int m = blockIdx.y;
  const float* A = Zin + (size_t)m*65536;
  const float* B = Yin + (size_t)m*65536;
  float* O = T + (size_t)m*65536;
  __shared__ float As[32][33], Bs[32][33];
  int t = threadIdx.x, tx = t & 15, ty = t >> 4;
  int m0 = (blockIdx.x >> 3) * 32, n0 = (blockIdx.x & 7) * 32;
  float acc[2][2] = {};
  for (int k0 = 0; k0 < 256; k0 += 32) {
#pragma unroll
    for (int l = 0; l < 4; l++) {
      int e = t + l * 256;
      int rr = e >> 5, cc = e & 31;
      As[rr][cc] = A[(size_t)(m0+rr)*256 + k0+cc];
      Bs[rr][cc] = B[(size_t)(k0+rr)*256 + n0+cc];
    }
    __syncthreads();
#pragma unroll
    for (int kk = 0; kk < 32; kk++) {
      float a0 = As[ty*2][kk], a1 = As[ty*2+1][kk];
      float b0 = Bs[kk][tx*2], b1 = Bs[kk][tx*2+1];
      acc[0][0] += a0*b0; acc[0][1] += a0*b1; acc[1][0] += a1*b0; acc[1][1] += a1*b1;
    }
    __syncthreads();
  }
#pragma unroll
  for (int a = 0; a < 2; a++)
#pragma unroll
    for (int b = 0; b < 2; b++) {
      int r = m0 + ty*2 + a, c = n0 + tx*2 + b;
      O[(size_t)r*256 + c] = (r == c) ? 3.f - acc[a][b] : -acc[a][b];
    }
}

// ---------------- NS phase B: Y'=0.5*Y*T (z=0), Z'=0.5*T*Z (z=1) ----------------
__global__ __launch_bounds__(256) void k_nsB(const float* Yin, const float* Zin, const float* T,
                                             float* Yout, float* Zout) {
  int m = blockIdx.y, z = blockIdx.z;
  const float* A = (z == 0 ? Yin : T) + (size_t)m*65536;
  const float* B = (z == 0 ? T : Zin) + (size_t)m*65536;
  float* O = (z == 0 ? Yout : Zout) + (size_t)m*65536;
  __shared__ float As[32][33], Bs[32][33];
  int t = threadIdx.x, tx = t & 15, ty = t >> 4;
  int m0 = (blockIdx.x >> 3) * 32, n0 = (blockIdx.x & 7) * 32;
  float acc[2][2] = {};
  for (int k0 = 0; k0 < 256; k0 += 32) {
#pragma unroll
    for (int l = 0; l < 4; l++) {
      int e = t + l * 256;
      int rr = e >> 5, cc = e & 31;
      As[rr][cc] = A[(size_t)(m0+rr)*256 + k0+cc];
      Bs[rr][cc] = B[(size_t)(k0+rr)*256 + n0+cc];
    }
    __syncthreads();
#pragma unroll
    for (int kk = 0; kk < 32; kk++) {
      float a0 = As[ty*2][kk], a1 = As[ty*2+1][kk];
      float b0 = Bs[kk][tx*2], b1 = Bs[kk][tx*2+1];
      acc[0][0] += a0*b0; acc[0][1] += a0*b1; acc[1][0] += a1*b0; acc[1][1] += a1*b1;
    }
    __syncthreads();
  }
#pragma unroll
  for (int a = 0; a < 2; a++)
#pragma unroll
    for (int b = 0; b < 2; b++)
      O[(size_t)(m0+ty*2+a)*256 + n0+tx*2+b] = 0.5f * acc[a][b];
}

// ---------------- whiten (all 4 matrices in grid.z): out = (1/sqrt(c))*Z@(x-mean) ----------------
__global__ __launch_bounds__(256) void k_whiten(const float* content, const float* style,
                                                const float* Zall, const float* means,
                                                const float* cnrm, float* nc, float* ns) {
  int m = blockIdx.z;
  const float* x = (m < 2 ? content : style) + (size_t)(m & 1) * CN;
  float* outp = (m < 2 ? nc : ns) + (size_t)(m & 1) * CN;
  const float* Zm = Zall + (size_t)m*65536;
  const float* mean = means + m*C_;
  __shared__ float As[16][68], Bs[16][64];
  int t = threadIdx.x, tx = t & 15, ty = t >> 4;
  int n0 = blockIdx.x * 64, m0 = blockIdx.y * 64;
  float acc[4][4] = {};
  for (int k0 = 0; k0 < 256; k0 += 16) {
#pragma unroll
    for (int l = 0; l < 4; l++) {
      int e = t + l*256;
      { int kk = e & 15, mm = e >> 4; As[kk][mm] = Zm[(size_t)(m0+mm)*256 + k0+kk]; }
      { int nn = e & 63, kk = e >> 6;
        Bs[kk][nn] = x[(size_t)(k0+kk)*N_ + n0+nn] - mean[k0+kk]; }
    }
    __syncthreads();
#pragma unroll
    for (int kk = 0; kk < 16; kk++) {
      float4 b = *(const float4*)&Bs[kk][tx*4];
      fma16(acc, As[kk][ty*4+0], As[kk][ty*4+1], As[kk][ty*4+2], As[kk][ty*4+3], b);
    }
    __syncthreads();
  }
  float scale = 1.0f / sqrtf(cnrm[m]);
#pragma unroll
  for (int i = 0; i < 4; i++) {
    float4 o = make_float4(acc[i][0]*scale, acc[i][1]*scale, acc[i][2]*scale, acc[i][3]*scale);
    *(float4*)&outp[(size_t)(m0+ty*4+i)*N_ + n0 + tx*4] = o;
  }
}

// ---------------- per-pixel channel sum-of-squares of ns ----------------
__global__ __launch_bounds__(256) void k_ssq(const float* ns, float* ssq) {
  int b = blockIdx.y; int p = blockIdx.x * 256 + threadIdx.x;
  float acc = 0.f;
  for (int c = 0; c < C_; c++) { float v = ns[(size_t)b*CN + (size_t)c*N_ + p]; acc += v*v; }
  ssq[b*N_ + p] = acc;
}

// ---------------- patch reciprocal norms ----------------
__global__ __launch_bounds__(256) void k_rnorm(const float* ssq, float* rnorm) {
  int b = blockIdx.y; int s = blockIdx.x * 256 + threadIdx.x;
  int sy = s >> 6, sx = s & 63;
  float sum = 0.f;
#pragma unroll
  for (int ky = 0; ky < 3; ky++)
#pragma unroll
    for (int kx = 0; kx < 3; kx++)
      sum += ssq[b*N_ + refl(sy+ky-1)*64 + refl(sx+kx-1)];
  rnorm[b*N_ + s] = 1.f / (sqrtf(sum) + EPSF);
}

// ---------------- transpose ns -> ns_t [b][pixel][channel] ----------------
__global__ __launch_bounds__(256) void k_transpose(const float* ns, float* ns_t) {
  int b = blockIdx.z;
  int u0 = blockIdx.x * 32, c0 = blockIdx.y * 32;
  __shared__ float tile[32][33];
  int t = threadIdx.x;
#pragma unroll
  for (int l = 0; l < 4; l++) {
    int e = t + l*256; int cc = e >> 5, uu = e & 31;
    tile[cc][uu] = ns[(size_t)b*CN + (size_t)(c0+cc)*N_ + u0+uu];
  }
  __syncthreads();
#pragma unroll
  for (int l = 0; l < 4; l++) {
    int e = t + l*256; int uu = e >> 5, cc = e & 31;
    ns_t[(size_t)b*CN + (size_t)(u0+uu)*C_ + c0+cc] = tile[cc][uu];
  }
}

// ---------------- Gram (128x128, 512 thr, acc 8x4, BK=32, single-buffer DMA staging) ----------------
// r10 config — the verified local optimum of this structure (112 us, VGPR 44, no spill).
// Pipelining post-mortems: r5/r9 register prefetch -> 128-VGPR cliff + scratch spill;
// r11 LDS double-buffer + DMA -> vmcnt(0) drained at every barrier (the m97 structural
// stall) AND 64 KB LDS halved occupancy (37%->22%, VALUBusy 65->50). High-occupancy
// implicit multi-wave overlap IS the latency-hiding mechanism; keep LDS small.
__global__ __launch_bounds__(512) void k_gram(const float* nc, const float* ns, float* Hx) {
  __shared__ float smem[64*133];   // As[32][128] + Bs[32][128] = 8192 floats; Gs[64][133] = 8512 (union)
  float* As = smem;
  float* Bs = smem + 4096;
  int t = threadIdx.x;
  int v0 = blockIdx.y * 128, u0 = blockIdx.x * 128;
  int wave = t >> 6, lane = t & 63;
  int wv = wave >> 1, wu = wave & 1;        // wave tile: rows wv*32..+31, cols wu*64..+63
  int ly = lane >> 4, lx = lane & 15;
  int srow = t >> 5, scol = (t & 31) * 4;   // 512 thr = 16 rows x 32 col-groups per pass
  float acc[8][4] = {};
  for (int k0 = 0; k0 < 256; k0 += 32) {
    __syncthreads();
#ifdef HAS_GLL
    __builtin_amdgcn_global_load_lds(
        (const __attribute__((address_space(1))) void*)&nc[(size_t)(k0+srow)*N_ + v0 + scol],
        (__attribute__((address_space(3))) void*)&As[srow*128 + scol], 16, 0, 0);
    __builtin_amdgcn_global_load_lds(
        (const __attribute__((address_space(1))) void*)&nc[(size_t)(k0+16+srow)*N_ + v0 + scol],
        (__attribute__((address_space(3))) void*)&As[(srow+16)*128 + scol], 16, 0, 0);
    __builtin_amdgcn_global_load_lds(
        (const __attribute__((address_space(1))) void*)&ns[(size_t)(k0+srow)*N_ + u0 + scol],
        (__attribute__((address_space(3))) void*)&Bs[srow*128 + scol], 16, 0, 0);
    __builtin_amdgcn_global_load_lds(
        (const __attribute__((address_space(1))) void*)&ns[(size_t)(k0+16+srow)*N_ + u0 + scol],
        (__attribute__((address_space(3))) void*)&Bs[(srow+16)*128 + scol], 16, 0, 0);
#else
    *(float4*)&As[srow*128 + scol]      = *(const float4*)&nc[(size_t)(k0+srow)*N_ + v0 + scol];
    *(float4*)&As[(srow+16)*128 + scol] = *(const float4*)&nc[(size_t)(k0+16+srow)*N_ + v0 + scol];
    *(float4*)&Bs[srow*128 + scol]      = *(const float4*)&ns[(size_t)(k0+srow)*N_ + u0 + scol];
    *(float4*)&Bs[(srow+16)*128 + scol] = *(const float4*)&ns[(size_t)(k0+16+srow)*N_ + u0 + scol];
#endif
    __syncthreads();
#pragma unroll
    for (int kk = 0; kk < 32; kk++) {
      float4 a0 = *(const float4*)&As[kk*128 + wv*32 + ly*8];      // lane-broadcast across lx
      float4 a1 = *(const float4*)&As[kk*128 + wv*32 + ly*8 + 4];
      float4 b0 = *(const float4*)&Bs[kk*128 + wu*64 + lx*4];
      float ar[8] = {a0.x,a0.y,a0.z,a0.w,a1.x,a1.y,a1.z,a1.w};
#pragma unroll
      for (int i = 0; i < 8; i++) {
        acc[i][0] += ar[i]*b0.x; acc[i][1] += ar[i]*b0.y;
        acc[i][2] += ar[i]*b0.z; acc[i][3] += ar[i]*b0.w;
      }
    }
  }
  // epilogue: per 64-row half h, x-diagonal blur. Gs stride 133 keeps writes <=2-way.
  float* Gs = smem;  // [64][133]
  int btx = t & 15, bty = t >> 4;            // bty 0..31
#pragma unroll
  for (int h = 0; h < 2; h++) {
    __syncthreads();
    if ((wv >> 1) == h) {                    // waves 2h, 2h+1 own rows h*64..h*64+63
      int rbase = (wv & 1) * 32;
#pragma unroll
      for (int i = 0; i < 8; i++) {
        int row = rbase + ly*8 + i;
#pragma unroll
        for (int j = 0; j < 4; j++)
          Gs[row*133 + wu*64 + lx*4 + j] = acc[i][j];
      }
    }
    __syncthreads();
#pragma unroll
    for (int i = 0; i < 2; i++) {
      int px = bty*2 + i;
      int xm = refl(px-1), xp = refl(px+1);
#pragma unroll
      for (int jh = 0; jh < 2; jh++) {       // col halves (sy blocks)
        int ub = jh*64;
        float tmp[4];
#pragma unroll
        for (int j = 0; j < 4; j++) {
          int sx = btx*4 + j;
          int sm = refl(sx-1), sp = refl(sx+1);
          tmp[j] = Gs[xm*133 + ub + sm] + Gs[px*133 + ub + sx] + Gs[xp*133 + ub + sp];
        }
        *(float4*)&Hx[(size_t)(v0 + h*64 + px)*N_ + u0 + ub + btx*4] =
            make_float4(tmp[0], tmp[1], tmp[2], tmp[3]);
      }
    }
  }
}

// ---------------- y-diagonal blur of Hx + argmax over style pixels ----------------
__global__ __launch_bounds__(256) void k_argmax(const float* Hx, const float* rnorm,
                                                int* idx, int b) {
  int p = blockIdx.x, t = threadIdx.x;
  int py = p >> 6, px = p & 63;
  size_t r0 = (size_t)(refl(py-1)*64 + px) * N_;
  size_t r1 = (size_t)p * N_;
  size_t r2 = (size_t)(refl(py+1)*64 + px) * N_;
  float bv = -1e30f; int bs = 0;
  for (int s = t; s < N_; s += 256) {
    int sy = s >> 6, sx = s & 63;
    int u0 = refl(sy-1)*64 + sx, u2 = refl(sy+1)*64 + sx;
    float acc = Hx[r0 + u0] + Hx[r1 + s] + Hx[r2 + u2];
    float sc = acc * rnorm[b*N_ + s];
    if (sc > bv) { bv = sc; bs = s; }   // ascending s -> first occurrence kept
  }
  __shared__ float sv[256]; __shared__ int si[256];
  sv[t] = bv; si[t] = bs; __syncthreads();
  for (int off = 128; off > 0; off >>= 1) {
    if (t < off) {
      if (sv[t+off] > sv[t] || (sv[t+off] == sv[t] && si[t+off] < si[t])) {
        sv[t] = sv[t+off]; si[t] = si[t+off];
      }
    }
    __syncthreads();
  }
  if (!t) idx[b*N_ + p] = si[0];
}

// ---------------- deconv gather: recont[b][p][c] ----------------
__global__ __launch_bounds__(256) void k_recon(const float* ns_t, const int* idx, float* recont) {
  int p = blockIdx.x, b = blockIdx.y, c = threadIdx.x;
  int py = p >> 6, px = p & 63;
  float acc = 0.f;
#pragma unroll
  for (int dy = 0; dy < 3; dy++)
#pragma unroll
    for (int dx = 0; dx < 3; dx++) {
      int q = refl(py+dy-1)*64 + refl(px+dx-1);
      int s = idx[b*N_ + q];
      int sy = s >> 6, sx = s & 63;
      int src = refl(sy+1-dy)*64 + refl(sx+1-dx);
      acc += ns_t[(size_t)b*CN + (size_t)src*C_ + c];
    }
  float dc = ((py==0||py==63)?2.f:3.f) * ((px==0||px==63)?2.f:3.f);
  recont[(size_t)b*CN + (size_t)p*C_ + c] = acc / dc;
}

// ---------------- coloring (both batches via grid.z): out = sqrt(c)*(Ys@recon)+smean ----------------
__global__ __launch_bounds__(256) void k_color(const float* Yall, const float* recont_all,
                                               const float* cnrm, const float* means,
                                               float* out_all) {
  int b = blockIdx.z;
  const float* Ym = Yall + (size_t)(2+b)*65536;
  const float* recont = recont_all + (size_t)b*CN;
  const float* smean = means + (2+b)*C_;
  float* out = out_all + (size_t)b*CN;
  __shared__ float As[16][68], Bs[16][68];
  int t = threadIdx.x, tx = t & 15, ty = t >> 4;
  int n0 = blockIdx.x * 64, m0 = blockIdx.y * 64;
  float acc[4][4] = {};
  for (int k0 = 0; k0 < 256; k0 += 16) {
#pragma unroll
    for (int l = 0; l < 4; l++) {
      int e = t + l*256;
      int kk = e & 15, q = e >> 4;
      As[kk][q] = Ym[(size_t)(m0+q)*256 + k0+kk];
      Bs[kk][q] = recont[(size_t)(n0+q)*256 + k0+kk];
    }
    __syncthreads();
#pragma unroll
    for (int kk = 0; kk < 16; kk++) {
      float4 b4 = make_float4(Bs[kk][tx*4+0], Bs[kk][tx*4+1], Bs[kk][tx*4+2], Bs[kk][tx*4+3]);
      fma16(acc, As[kk][ty*4+0], As[kk][ty*4+1], As[kk][ty*4+2], As[kk][ty*4+3], b4);
    }
    __syncthreads();
  }
  float scale = sqrtf(cnrm[2+b]);
#pragma unroll
  for (int i = 0; i < 4; i++) {
    int r = m0 + ty*4 + i;
    float sm = smean[r];
    float4 o = make_float4(acc[i][0]*scale + sm, acc[i][1]*scale + sm,
                           acc[i][2]*scale + sm, acc[i][3]*scale + sm);
    *(float4*)&out[(size_t)r*N_ + n0 + tx*4] = o;
  }
}

extern "C" void kernel_launch(void* const* d_in, const int* in_sizes, int n_in,
                              void* d_out, int out_size, void* d_ws, size_t ws_size,
                              hipStream_t stream) {
  const float* content = (const float*)d_in[0];
  const float* style   = (const float*)d_in[1];
  float* out = (float*)d_out;

  // workspace layout (floats); total ~107 MiB
  float* F = (float*)d_ws;
  float* means  = F + 0;         // 4*256
  float* cnrm   = F + 1024;      // 4
  float* Y      = F + 264192;
  float* Z      = F + 526336;
  float* Y2     = F + 788480;
  float* Z2     = F + 1050624;
  float* T      = F + 1312768;
  float* nc     = F + 1574912;   // 2*CN
  float* ns     = F + 3672064;   // 2*CN
  float* ns_t   = F + 5769216;   // 2*CN
  float* recont = F + 7866368;   // 2*CN
  float* ssq    = F + 9963520;   // 2*4096
  float* rnorm  = F + 9971712;   // 2*4096
  int*   idx    = (int*)(F + 9979904); // 2*4096
  float* Hx     = F + 9988096;   // 4096*4096 (reused per batch)

  // split-K cov partials (8 MB) alias the nc buffer: consumed by k_trace2/k_covred_init
  // before k_whiten writes nc (stream-serialized).
  float* covp = nc;

  // 1. per-channel means
  k_mean<<<dim3(256,4), 256, 0, stream>>>(content, style, means);
  // 2. covariance raw sums, split-K (2048 blocks)
  k_cov<<<dim3(64,4,KSPLIT), 256, 0, stream>>>(content, style, covp);
  // 3. trace from partials -> cnrm = (tr/256)*1.3 (spectrum-centered NS scaling)
  k_trace2<<<4, 256, 0, stream>>>(covp, means, cnrm);
  // 4. merged covred + NS init (cov matrix never materialized)
  k_covred_init<<<dim3(256,4), 256, 0, stream>>>(covp, means, cnrm, Y, Z);
  // 5. NS iterations, discrete launches (r7: grid barriers cost ~40us each — launches win).
  float *Ya = Y, *Za = Z, *Yb = Y2, *Zb = Z2;
  for (int it = 0; it < NS_ITERS; it++) {
    k_nsA<<<dim3(64,4), 256, 0, stream>>>(Za, Ya, T);
    k_nsB<<<dim3(64,4,2), 256, 0, stream>>>(Ya, Za, T, Yb, Zb);
    float* tmp;
    tmp = Ya; Ya = Yb; Yb = tmp;
    tmp = Za; Za = Zb; Zb = tmp;
  }
  // 6. whitening: nc, ns (all 4 matrices, one launch); NS_ITERS even -> results in Y,Z
  k_whiten<<<dim3(64,4,4), 256, 0, stream>>>(content, style, Za, means, cnrm, nc, ns);
  // 7. patch norms of whitened style
  k_ssq<<<dim3(16,2), 256, 0, stream>>>(ns, ssq);
  k_rnorm<<<dim3(16,2), 256, 0, stream>>>(ssq, rnorm);
  // 8. pixel-major transpose of ns for the recon gather
  k_transpose<<<dim3(128,8,2), 256, 0, stream>>>(ns, ns_t);
  // 9. per batch: Gram+x-blur (BK=32, DMA staging), then y-blur+argmax
  for (int b = 0; b < 2; b++) {
    k_gram<<<dim3(32,32), 512, 0, stream>>>(nc + (size_t)b*CN, ns + (size_t)b*CN, Hx);
    k_argmax<<<4096, 256, 0, stream>>>(Hx, rnorm, idx, b);
  }
  // 10. deconv gather + deconv-norm division
  k_recon<<<dim3(4096,2), 256, 0, stream>>>(ns_t, idx, recont);
  // 11. coloring with style stats (both batches, one launch)
  k_color<<<dim3(64,4,2), 256, 0, stream>>>(Ya, recont, cnrm, means, out);
}

// Round 14
// 530.241 us; speedup vs baseline: 1.3418x; 1.1370x over previous
//
#include <hip/hip_runtime.h>
#include <hip/hip_bf16.h>

#define C_ 256
#define N_ 4096
#define CN (C_*N_)
#define EPSF 1e-5f
#define NS_ITERS 6
#define KSPLIT 8
#define LSTR 40   // LDS row stride in ushort: 80 B, 16B-aligned, 2-way banks (free)

typedef short bf16x8 __attribute__((ext_vector_type(8)));
typedef float f32x4 __attribute__((ext_vector_type(4)));

__device__ __forceinline__ int refl(int t) {
  return t < 0 ? -t : (t > 63 ? 126 - t : t);
}

__device__ __forceinline__ unsigned short f2bf(float x) {
  unsigned u = __float_as_uint(x);
  unsigned r = (u + 0x7FFFu + ((u >> 16) & 1u)) >> 16;
  return (unsigned short)r;
}
__device__ __forceinline__ float bf2f(unsigned short h) {
  return __uint_as_float((unsigned)h << 16);
}

__device__ __forceinline__ void fma16(float acc[4][4], float a0, float a1, float a2, float a3, float4 b) {
  acc[0][0] += a0*b.x; acc[0][1] += a0*b.y; acc[0][2] += a0*b.z; acc[0][3] += a0*b.w;
  acc[1][0] += a1*b.x; acc[1][1] += a1*b.y; acc[1][2] += a1*b.z; acc[1][3] += a1*b.w;
  acc[2][0] += a2*b.x; acc[2][1] += a2*b.y; acc[2][2] += a2*b.z; acc[2][3] += a2*b.w;
  acc[3][0] += a3*b.x; acc[3][1] += a3*b.y; acc[3][2] += a3*b.z; acc[3][3] += a3*b.w;
}

// ---------------- means ----------------
__global__ __launch_bounds__(256) void k_mean(const float* content, const float* style,
                                              float* means) {
  int c = blockIdx.x, m = blockIdx.y, t = threadIdx.x;
  const float* x = (m < 2 ? content : style) + (size_t)(m & 1) * CN + (size_t)c * N_;
  float s = 0.f;
  for (int i = t; i < N_; i += 256) s += x[i];
  __shared__ float red[256];
  red[t] = s; __syncthreads();
  for (int off = 128; off > 0; off >>= 1) { if (t < off) red[t] += red[t + off]; __syncthreads(); }
  if (t == 0) means[m * C_ + c] = red[0] * (1.f / N_);
}

// ---------------- covariance raw sums, split-K ----------------
__global__ __launch_bounds__(256) void k_cov(const float* content, const float* style,
                                             float* covp) {
  int m = blockIdx.y, kc = blockIdx.z;
  int ti = blockIdx.x >> 3, tj = blockIdx.x & 7;
  int t = threadIdx.x, tx = t & 15, ty = t >> 4;
  const float* x = (m < 2 ? content : style) + (size_t)(m & 1) * CN;
  __shared__ float As[32][33], Bs[32][33];
  float acc[2][2] = {};
  int i0 = ti * 32, j0 = tj * 32;
  int kbeg = kc * (N_ / KSPLIT), kend = kbeg + (N_ / KSPLIT);
  for (int k0 = kbeg; k0 < kend; k0 += 32) {
#pragma unroll
    for (int l = 0; l < 4; l++) {
      int e = t + l * 256;
      int rr = e >> 5, nn = e & 31;
      As[rr][nn] = x[(size_t)(i0 + rr) * N_ + k0 + nn];
      Bs[rr][nn] = x[(size_t)(j0 + rr) * N_ + k0 + nn];
    }
    __syncthreads();
#pragma unroll
    for (int kk = 0; kk < 32; kk++) {
      float a0 = As[ty*2][kk], a1 = As[ty*2+1][kk];
      float b0 = Bs[tx*2][kk], b1 = Bs[tx*2+1][kk];
      acc[0][0] += a0*b0; acc[0][1] += a0*b1; acc[1][0] += a1*b0; acc[1][1] += a1*b1;
    }
    __syncthreads();
  }
#pragma unroll
  for (int a = 0; a < 2; a++)
#pragma unroll
    for (int b = 0; b < 2; b++)
      covp[((size_t)kc*4 + m)*65536 + (size_t)(i0 + ty*2 + a)*C_ + (j0 + tx*2 + b)] = acc[a][b];
}

// ---------------- trace from partials -> cnrm = (tr/256)*1.3 ----------------
__global__ __launch_bounds__(256) void k_trace2(const float* covp, const float* means,
                                                float* cnrm) {
  int m = blockIdx.x, t = threadIdx.x;
  float s = 0.f;
#pragma unroll
  for (int kc = 0; kc < KSPLIT; kc++)
    s += covp[((size_t)kc*4 + m)*65536 + (size_t)t*257];
  float mi = means[m*C_ + t];
  float d = (s - (float)N_*mi*mi) * (1.f/(float)(N_-1));
  __shared__ float red[256];
  red[t] = d; __syncthreads();
  for (int off = 128; off > 0; off >>= 1) { if (t < off) red[t] += red[t + off]; __syncthreads(); }
  if (!t) cnrm[m] = red[0] * (1.3f/256.f);
}

// ---------------- merged covred + nsinit ----------------
__global__ __launch_bounds__(256) void k_covred_init(const float* covp, const float* means,
                                                     const float* cnrm, float* Y, float* Z) {
  int i = blockIdx.x, m = blockIdx.y, j = threadIdx.x;
  float s = 0.f;
#pragma unroll
  for (int kc = 0; kc < KSPLIT; kc++)
    s += covp[((size_t)kc*4 + m)*65536 + (size_t)i*C_ + j];
  float mi = means[m*C_ + i], mj = means[m*C_ + j];
  float cv = (s - (float)N_*mi*mj) * (1.f/(float)(N_-1));
  size_t o = (size_t)m*65536 + (size_t)i*C_ + j;
  Y[o] = cv / cnrm[m];
  Z[o] = (i == j) ? 1.f : 0.f;
}

// ---------------- NS phase A: T = 3I - Z*Y ----------------
__global__ __launch_bounds__(256) void k_nsA(const float* Zin, const float* Yin, float* T) {
  int m = blockIdx.y;
  const float* A = Zin + (size_t)m*65536;
  const float* B = Yin + (size_t)m*65536;
  float* O = T + (size_t)m*65536;
  __shared__ float As[32][33], Bs[32][33];
  int t = threadIdx.x, tx = t & 15, ty = t >> 4;
  int m0 = (blockIdx.x >> 3) * 32, n0 = (blockIdx.x & 7) * 32;
  float acc[2][2] = {};
  for (int k0 = 0; k0 < 256; k0 += 32) {
#pragma unroll
    for (int l = 0; l < 4; l++) {
      int e = t + l * 256;
      int rr = e >> 5, cc = e & 31;
      As[rr][cc] = A[(size_t)(m0+rr)*256 + k0+cc];
      Bs[rr][cc] = B[(size_t)(k0+rr)*256 + n0+cc];
    }
    __syncthreads();
#pragma unroll
    for (int kk = 0; kk < 32; kk++) {
      float a0 = As[ty*2][kk], a1 = As[ty*2+1][kk];
      float b0 = Bs[kk][tx*2], b1 = Bs[kk][tx*2+1];
      acc[0][0] += a0*b0; acc[0][1] += a0*b1; acc[1][0] += a1*b0; acc[1][1] += a1*b1;
    }
    __syncthreads();
  }
#pragma unroll
  for (int a = 0; a < 2; a++)
#pragma unroll
    for (int b = 0; b < 2; b++) {
      int r = m0 + ty*2 + a, c = n0 + tx*2 + b;
      O[(size_t)r*256 + c] = (r == c) ? 3.f - acc[a][b] : -acc[a][b];
    }
}

// ---------------- NS phase B ----------------
__global__ __launch_bounds__(256) void k_nsB(const float* Yin, const float* Zin, const float* T,
                                             float* Yout, float* Zout) {
  int m = blockIdx.y, z = blockIdx.z;
  const float* A = (z == 0 ? Yin : T) + (size_t)m*65536;
  const float* B = (z == 0 ? T : Zin) + (size_t)m*65536;
  float* O = (z == 0 ? Yout : Zout) + (size_t)m*65536;
  __shared__ float As[32][33], Bs[32][33];
  int t = threadIdx.x, tx = t & 15, ty = t >> 4;
  int m0 = (blockIdx.x >> 3) * 32, n0 = (blockIdx.x & 7) * 32;
  float acc[2][2] = {};
  for (int k0 = 0; k0 < 256; k0 += 32) {
#pragma unroll
    for (int l = 0; l < 4; l++) {
      int e = t + l * 256;
      int rr = e >> 5, cc = e & 31;
      As[rr][cc] = A[(size_t)(m0+rr)*256 + k0+cc];
      Bs[rr][cc] = B[(size_t)(k0+rr)*256 + n0+cc];
    }
    __syncthreads();
#pragma unroll
    for (int kk = 0; kk < 32; kk++) {
      float a0 = As[ty*2][kk], a1 = As[ty*2+1][kk];
      float b0 = Bs[kk][tx*2], b1 = Bs[kk][tx*2+1];
      acc[0][0] += a0*b0; acc[0][1] += a0*b1; acc[1][0] += a1*b0; acc[1][1] += a1*b1;
    }
    __syncthreads();
  }
#pragma unroll
  for (int a = 0; a < 2; a++)
#pragma unroll
    for (int b = 0; b < 2; b++)
      O[(size_t)(m0+ty*2+a)*256 + n0+tx*2+b] = 0.5f * acc[a][b];
}

// ---------------- whiten ----------------
__global__ __launch_bounds__(256) void k_whiten(const float* content, const float* style,
                                                const float* Zall, const float* means,
                                                const float* cnrm, float* nc, float* ns) {
  int m = blockIdx.z;
  const float* x = (m < 2 ? content : style) + (size_t)(m & 1) * CN;
  float* outp = (m < 2 ? nc : ns) + (size_t)(m & 1) * CN;
  const float* Zm = Zall + (size_t)m*65536;
  const float* mean = means + m*C_;
  __shared__ float As[16][68], Bs[16][64];
  int t = threadIdx.x, tx = t & 15, ty = t >> 4;
  int n0 = blockIdx.x * 64, m0 = blockIdx.y * 64;
  float acc[4][4] = {};
  for (int k0 = 0; k0 < 256; k0 += 16) {
#pragma unroll
    for (int l = 0; l < 4; l++) {
      int e = t + l*256;
      { int kk = e & 15, mm = e >> 4; As[kk][mm] = Zm[(size_t)(m0+mm)*256 + k0+kk]; }
      { int nn = e & 63, kk = e >> 6;
        Bs[kk][nn] = x[(size_t)(k0+kk)*N_ + n0+nn] - mean[k0+kk]; }
    }
    __syncthreads();
#pragma unroll
    for (int kk = 0; kk < 16; kk++) {
      float4 b = *(const float4*)&Bs[kk][tx*4];
      fma16(acc, As[kk][ty*4+0], As[kk][ty*4+1], As[kk][ty*4+2], As[kk][ty*4+3], b);
    }
    __syncthreads();
  }
  float scale = 1.0f / sqrtf(cnrm[m]);
#pragma unroll
  for (int i = 0; i < 4; i++) {
    float4 o = make_float4(acc[i][0]*scale, acc[i][1]*scale, acc[i][2]*scale, acc[i][3]*scale);
    *(float4*)&outp[(size_t)(m0+ty*4+i)*N_ + n0 + tx*4] = o;
  }
}

// ---------------- per-pixel channel sum-of-squares of ns ----------------
__global__ __launch_bounds__(256) void k_ssq(const float* ns, float* ssq) {
  int b = blockIdx.y; int p = blockIdx.x * 256 + threadIdx.x;
  float acc = 0.f;
  for (int c = 0; c < C_; c++) { float v = ns[(size_t)b*CN + (size_t)c*N_ + p]; acc += v*v; }
  ssq[b*N_ + p] = acc;
}

// ---------------- patch reciprocal norms ----------------
__global__ __launch_bounds__(256) void k_rnorm(const float* ssq, float* rnorm) {
  int b = blockIdx.y; int s = blockIdx.x * 256 + threadIdx.x;
  int sy = s >> 6, sx = s & 63;
  float sum = 0.f;
#pragma unroll
  for (int ky = 0; ky < 3; ky++)
#pragma unroll
    for (int kx = 0; kx < 3; kx++)
      sum += ssq[b*N_ + refl(sy+ky-1)*64 + refl(sx+kx-1)];
  rnorm[b*N_ + s] = 1.f / (sqrtf(sum) + EPSF);
}

// ---------------- transpose + 3-way bf16 split for ONE batch: [c][v] -> [v][c] h/m/l ----------------
// z=0: nc_b -> ncT planes ; z=1: ns_b -> nsT planes. v = h+m+l to ~2^-27 rel.
__global__ __launch_bounds__(256) void k_split(const float* nc_b, const float* ns_b,
                                               unsigned short* ncTh, unsigned short* ncTm,
                                               unsigned short* ncTl,
                                               unsigned short* nsTh, unsigned short* nsTm,
                                               unsigned short* nsTl) {
  int w = blockIdx.z;
  const float* src = w ? ns_b : nc_b;
  unsigned short* dh = w ? nsTh : ncTh;
  unsigned short* dm = w ? nsTm : ncTm;
  unsigned short* dl = w ? nsTl : ncTl;
  int u0 = blockIdx.x * 32, c0 = blockIdx.y * 32;
  __shared__ float tile[32][33];
  int t = threadIdx.x;
#pragma unroll
  for (int l = 0; l < 4; l++) {
    int e = t + l*256; int cc = e >> 5, uu = e & 31;
    tile[cc][uu] = src[(size_t)(c0+cc)*N_ + u0+uu];
  }
  __syncthreads();
#pragma unroll
  for (int l = 0; l < 4; l++) {
    int e = t + l*256; int uu = e >> 5, cc = e & 31;
    float v = tile[cc][uu];
    unsigned short h = f2bf(v);
    float r1 = v - bf2f(h);
    unsigned short m = f2bf(r1);
    float r2 = r1 - bf2f(m);
    unsigned short lo = f2bf(r2);
    size_t o = (size_t)(u0+uu)*C_ + c0+cc;
    dh[o] = h; dm[o] = m; dl[o] = lo;
  }
}

// ---------------- Gram via 3-way-split bf16 MFMA (128x128 tile, 512 thr) + fused x-blur ----------------
// G = hh + hm + mh + hl + lh + mm  (6 x mfma_f32_16x16x32_bf16; dropped terms <= 2^-27 rel
// -> fp32-accurate scores, zero argmax-flip risk vs the np fp32 reference).
// Wave tiling: 8 waves, rows wv*32..+31 (wv=wave>>1), cols wu*64..+63 (wu=wave&1), 2x4 16x16 tiles.
// A-frag [m=lane&15][k=quad*8+j] (m120); B-frag symmetric; C/D col=lane&15,row=quad*4+reg (m89/m91).
// LDS stride 40 ushorts: 16B-aligned b128 frags, 2-way banks (free). Plain float4 staging
// (GLL needs unpadded rows; r10 note). acc = 32 VGPR, frags short-lived -> no VGPR cliff.
__global__ __launch_bounds__(512) void k_gram(const unsigned short* Ah_g, const unsigned short* Am_g,
                                              const unsigned short* Al_g,
                                              const unsigned short* Bh_g, const unsigned short* Bm_g,
                                              const unsigned short* Bl_g, float* Hx) {
  __shared__ unsigned short sm[6*128*LSTR];  // 61440 B; epilogue Gs[64][133] fp32 (34048 B) unioned
  const int P = 128*LSTR;
  int t = threadIdx.x;
  int v0 = blockIdx.y * 128, u0 = blockIdx.x * 128;
  int wave = t >> 6, lane = t & 63;
  int wv = wave >> 1, wu = wave & 1;
  int lx16 = lane & 15, quad = lane >> 4;
  int srow = t >> 2, sseg = (t & 3) * 8;     // 512 thr = 128 rows x 4 segs of 8 ushort (16 B)
  f32x4 acc[2][4];
#pragma unroll
  for (int i = 0; i < 2; i++)
#pragma unroll
    for (int j = 0; j < 4; j++) acc[i][j] = (f32x4){0.f, 0.f, 0.f, 0.f};

  for (int k0 = 0; k0 < 256; k0 += 32) {
    __syncthreads();
    {
      size_t goA = (size_t)(v0 + srow)*C_ + k0 + sseg;
      size_t goB = (size_t)(u0 + srow)*C_ + k0 + sseg;
      int lo_ = srow*LSTR + sseg;
      *(float4*)&sm[0*P + lo_] = *(const float4*)&Ah_g[goA];
      *(float4*)&sm[1*P + lo_] = *(const float4*)&Am_g[goA];
      *(float4*)&sm[2*P + lo_] = *(const float4*)&Al_g[goA];
      *(float4*)&sm[3*P + lo_] = *(const float4*)&Bh_g[goB];
      *(float4*)&sm[4*P + lo_] = *(const float4*)&Bm_g[goB];
      *(float4*)&sm[5*P + lo_] = *(const float4*)&Bl_g[goB];
    }
    __syncthreads();
#pragma unroll
    for (int mt = 0; mt < 2; mt++) {
      int arow = (wv*32 + mt*16 + lx16)*LSTR + quad*8;
      bf16x8 ah = *(const bf16x8*)&sm[0*P + arow];
      bf16x8 am = *(const bf16x8*)&sm[1*P + arow];
      bf16x8 al = *(const bf16x8*)&sm[2*P + arow];
#pragma unroll
      for (int nt = 0; nt < 4; nt++) {
        int brow = (wu*64 + nt*16 + lx16)*LSTR + quad*8;
        bf16x8 bh = *(const bf16x8*)&sm[3*P + brow];
        bf16x8 bm = *(const bf16x8*)&sm[4*P + brow];
        bf16x8 bl = *(const bf16x8*)&sm[5*P + brow];
        f32x4 a = acc[mt][nt];
        a = __builtin_amdgcn_mfma_f32_16x16x32_bf16(ah, bh, a, 0, 0, 0);
        a = __builtin_amdgcn_mfma_f32_16x16x32_bf16(ah, bm, a, 0, 0, 0);
        a = __builtin_amdgcn_mfma_f32_16x16x32_bf16(am, bh, a, 0, 0, 0);
        a = __builtin_amdgcn_mfma_f32_16x16x32_bf16(ah, bl, a, 0, 0, 0);
        a = __builtin_amdgcn_mfma_f32_16x16x32_bf16(al, bh, a, 0, 0, 0);
        a = __builtin_amdgcn_mfma_f32_16x16x32_bf16(am, bm, a, 0, 0, 0);
        acc[mt][nt] = a;
      }
    }
  }
  // epilogue: per 64-row half h, x-diagonal blur. Gs stride 133 fp32.
  float* Gs = (float*)sm;
  int btx = t & 15, bty = t >> 4;            // bty 0..31
#pragma unroll
  for (int h = 0; h < 2; h++) {
    __syncthreads();
    if ((wv >> 1) == h) {                    // waves with wv in {2h,2h+1} own rows h*64..+63
      int rbase = (wv & 1) * 32;
#pragma unroll
      for (int mt = 0; mt < 2; mt++)
#pragma unroll
        for (int nt = 0; nt < 4; nt++)
#pragma unroll
          for (int i = 0; i < 4; i++)
            Gs[(rbase + mt*16 + quad*4 + i)*133 + wu*64 + nt*16 + lx16] = acc[mt][nt][i];
    }
    __syncthreads();
#pragma unroll
    for (int i = 0; i < 2; i++) {
      int px = bty*2 + i;
      int xm = refl(px-1), xp = refl(px+1);
#pragma unroll
      for (int jh = 0; jh < 2; jh++) {
        int ub = jh*64;
        float tmp[4];
#pragma unroll
        for (int j = 0; j < 4; j++) {
          int sx = btx*4 + j;
          int smm = refl(sx-1), sp = refl(sx+1);
          tmp[j] = Gs[xm*133 + ub + smm] + Gs[px*133 + ub + sx] + Gs[xp*133 + ub + sp];
        }
        *(float4*)&Hx[(size_t)(v0 + h*64 + px)*N_ + u0 + ub + btx*4] =
            make_float4(tmp[0], tmp[1], tmp[2], tmp[3]);
      }
    }
  }
}

// ---------------- y-diagonal blur of Hx + argmax ----------------
__global__ __launch_bounds__(256) void k_argmax(const float* Hx, const float* rnorm,
                                                int* idx, int b) {
  int p = blockIdx.x, t = threadIdx.x;
  int py = p >> 6, px = p & 63;
  size_t r0 = (size_t)(refl(py-1)*64 + px) * N_;
  size_t r1 = (size_t)p * N_;
  size_t r2 = (size_t)(refl(py+1)*64 + px) * N_;
  float bv = -1e30f; int bs = 0;
  for (int s = t; s < N_; s += 256) {
    int sy = s >> 6, sx = s & 63;
    int u0 = refl(sy-1)*64 + sx, u2 = refl(sy+1)*64 + sx;
    float acc = Hx[r0 + u0] + Hx[r1 + s] + Hx[r2 + u2];
    float sc = acc * rnorm[b*N_ + s];
    if (sc > bv) { bv = sc; bs = s; }
  }
  __shared__ float sv[256]; __shared__ int si[256];
  sv[t] = bv; si[t] = bs; __syncthreads();
  for (int off = 128; off > 0; off >>= 1) {
    if (t < off) {
      if (sv[t+off] > sv[t] || (sv[t+off] == sv[t] && si[t+off] < si[t])) {
        sv[t] = sv[t+off]; si[t] = si[t+off];
      }
    }
    __syncthreads();
  }
  if (!t) idx[b*N_ + p] = si[0];
}

// ---------------- deconv gather for batch b: recont_b[p][c] from bf16 triple ----------------
__global__ __launch_bounds__(256) void k_recon(const unsigned short* nsTh,
                                               const unsigned short* nsTm,
                                               const unsigned short* nsTl,
                                               const int* idx_b, float* recont_b) {
  int p = blockIdx.x, c = threadIdx.x;
  int py = p >> 6, px = p & 63;
  float acc = 0.f;
#pragma unroll
  for (int dy = 0; dy < 3; dy++)
#pragma unroll
    for (int dx = 0; dx < 3; dx++) {
      int q = refl(py+dy-1)*64 + refl(px+dx-1);
      int s = idx_b[q];
      int sy = s >> 6, sx = s & 63;
      size_t o = (size_t)(refl(sy+1-dy)*64 + refl(sx+1-dx))*C_ + c;
      acc += bf2f(nsTh[o]) + bf2f(nsTm[o]) + bf2f(nsTl[o]);
    }
  float dc = ((py==0||py==63)?2.f:3.f) * ((px==0||px==63)?2.f:3.f);
  recont_b[(size_t)p*C_ + c] = acc / dc;
}

// ---------------- coloring (both batches via grid.z) ----------------
__global__ __launch_bounds__(256) void k_color(const float* Yall, const float* recont_all,
                                               const float* cnrm, const float* means,
                                               float* out_all) {
  int b = blockIdx.z;
  const float* Ym = Yall + (size_t)(2+b)*65536;
  const float* recont = recont_all + (size_t)b*CN;
  const float* smean = means + (2+b)*C_;
  float* out = out_all + (size_t)b*CN;
  __shared__ float As[16][68], Bs[16][68];
  int t = threadIdx.x, tx = t & 15, ty = t >> 4;
  int n0 = blockIdx.x * 64, m0 = blockIdx.y * 64;
  float acc[4][4] = {};
  for (int k0 = 0; k0 < 256; k0 += 16) {
#pragma unroll
    for (int l = 0; l < 4; l++) {
      int e = t + l*256;
      int kk = e & 15, q = e >> 4;
      As[kk][q] = Ym[(size_t)(m0+q)*256 + k0+kk];
      Bs[kk][q] = recont[(size_t)(n0+q)*256 + k0+kk];
    }
    __syncthreads();
#pragma unroll
    for (int kk = 0; kk < 16; kk++) {
      float4 b4 = make_float4(Bs[kk][tx*4+0], Bs[kk][tx*4+1], Bs[kk][tx*4+2], Bs[kk][tx*4+3]);
      fma16(acc, As[kk][ty*4+0], As[kk][ty*4+1], As[kk][ty*4+2], As[kk][ty*4+3], b4);
    }
    __syncthreads();
  }
  float scale = sqrtf(cnrm[2+b]);
#pragma unroll
  for (int i = 0; i < 4; i++) {
    int r = m0 + ty*4 + i;
    float sm = smean[r];
    float4 o = make_float4(acc[i][0]*scale + sm, acc[i][1]*scale + sm,
                           acc[i][2]*scale + sm, acc[i][3]*scale + sm);
    *(float4*)&out[(size_t)r*N_ + n0 + tx*4] = o;
  }
}

extern "C" void kernel_launch(void* const* d_in, const int* in_sizes, int n_in,
                              void* d_out, int out_size, void* d_ws, size_t ws_size,
                              hipStream_t stream) {
  const float* content = (const float*)d_in[0];
  const float* style   = (const float*)d_in[1];
  float* out = (float*)d_out;

  // workspace layout (floats); total ~102 MiB (verified budget — r13's overflow fixed)
  float* F = (float*)d_ws;
  float* means  = F + 0;         // 4*256
  float* cnrm   = F + 1024;      // 4
  float* Y      = F + 264192;    // NS buffers, 256KB each region of 4 matrices
  float* Z      = F + 526336;
  float* Y2     = F + 788480;    // free after NS (NS_ITERS=6 even -> results in Y,Z)
  float* Z2     = F + 1050624;
  float* T      = F + 1312768;
  float* nc     = F + 1574912;   // 2*CN fp32 (dead after split(1))
  float* ns     = F + 3672064;   // 2*CN fp32 (dead after split(1))
  float* nstslot= F + 5769216;   // old ns_t slot: 2*CN floats = 4 bf16 planes
  float* recont = F + 7866368;   // 2*CN fp32, written per batch at recon(b)
  float* ssq    = F + 9963520;   // 2*4096
  float* rnorm  = F + 9971712;   // 2*4096
  int*   idx    = (int*)(F + 9979904); // 2*4096
  float* Hx     = F + 9988096;   // 4096*4096

  float* covp = nc;  // split-K cov partials alias nc (consumed pre-whiten)

  // per-batch bf16 planes (each CN ushorts = 2 MB), race-checked vs launch order:
  //  - nsT h/m/l + ncT h: the 4 slots of the old ns_t region (recon reads nsT* only)
  //  - ncT m: Y2+Z2 (free post-NS)
  //  - ncT l: recont[1] head — written at split(b), dead after gram(b); recon(1)
  //    overwrites it only AFTER gram(1). recon(0) writes recont[0] (disjoint).
  unsigned short* nsTh = (unsigned short*)nstslot;
  unsigned short* nsTm = (unsigned short*)nstslot + (size_t)CN;
  unsigned short* nsTl = (unsigned short*)nstslot + 2*(size_t)CN;
  unsigned short* ncTh = (unsigned short*)nstslot + 3*(size_t)CN;
  unsigned short* ncTm = (unsigned short*)Y2;
  unsigned short* ncTl = (unsigned short*)(recont + CN);

  // 1-4. means, cov partials, trace, covred+nsinit
  k_mean<<<dim3(256,4), 256, 0, stream>>>(content, style, means);
  k_cov<<<dim3(64,4,KSPLIT), 256, 0, stream>>>(content, style, covp);
  k_trace2<<<4, 256, 0, stream>>>(covp, means, cnrm);
  k_covred_init<<<dim3(256,4), 256, 0, stream>>>(covp, means, cnrm, Y, Z);
  // 5. NS iterations (6, even -> results land back in Y,Z; Y2/Z2/T free afterwards)
  float *Ya = Y, *Za = Z, *Yb = Y2, *Zb = Z2;
  for (int it = 0; it < NS_ITERS; it++) {
    k_nsA<<<dim3(64,4), 256, 0, stream>>>(Za, Ya, T);
    k_nsB<<<dim3(64,4,2), 256, 0, stream>>>(Ya, Za, T, Yb, Zb);
    float* tmp;
    tmp = Ya; Ya = Yb; Yb = tmp;
    tmp = Za; Za = Zb; Zb = tmp;
  }
  // 6. whitening
  k_whiten<<<dim3(64,4,4), 256, 0, stream>>>(content, style, Za, means, cnrm, nc, ns);
  // 7. patch norms
  k_ssq<<<dim3(16,2), 256, 0, stream>>>(ns, ssq);
  k_rnorm<<<dim3(16,2), 256, 0, stream>>>(ssq, rnorm);
  // 8. per batch: split -> MFMA gram + x-blur -> y-blur+argmax -> recon
  for (int b = 0; b < 2; b++) {
    k_split<<<dim3(128,8,2), 256, 0, stream>>>(nc + (size_t)b*CN, ns + (size_t)b*CN,
                                               ncTh, ncTm, ncTl, nsTh, nsTm, nsTl);
    k_gram<<<dim3(32,32), 512, 0, stream>>>(ncTh, ncTm, ncTl, nsTh, nsTm, nsTl, Hx);
    k_argmax<<<4096, 256, 0, stream>>>(Hx, rnorm, idx, b);
    k_recon<<<4096, 256, 0, stream>>>(nsTh, nsTm, nsTl, idx + (size_t)b*N_,
                                      recont + (size_t)b*CN);
  }
  // 9. coloring
  k_color<<<dim3(64,4,2), 256, 0, stream>>>(Ya, recont, cnrm, means, out);
}